// Round 13
// baseline (201.964 us; speedup 1.0000x reference)
//
#include <hip/hip_runtime.h>
#include <stdint.h>

typedef short s16x8 __attribute__((ext_vector_type(8)));
typedef float f32x4 __attribute__((ext_vector_type(4)));
typedef unsigned short u16;
typedef unsigned int u32;

__device__ __forceinline__ float bf2f(u16 u) {
  union { u32 i; float f; } v; v.i = ((u32)u) << 16; return v.f;
}
__device__ __forceinline__ u16 f2bf(float f) {  // round-to-nearest-even
  union { float f; u32 i; } v; v.f = f;
  u32 i = v.i;
  return (u16)((i + 0x7fffu + ((i >> 16) & 1u)) >> 16);
}
__device__ __forceinline__ u16 f2bf_fast(float f) {  // round-half-up
  union { float f; u32 i; } v; v.f = f;
  return (u16)((v.i + 0x8000u) >> 16);
}

__device__ __forceinline__ s16x8 load8(const void* p, size_t idx, int isf32) {
  s16x8 r;
  if (isf32) {
    const float* f = (const float*)p + idx;
    f32x4 a = *(const f32x4*)f;
    f32x4 b = *(const f32x4*)(f + 4);
#pragma unroll
    for (int j = 0; j < 4; j++) {
      r[j] = (short)f2bf(a[j]);
      r[4 + j] = (short)f2bf(b[j]);
    }
  } else {
    r = *(const s16x8*)((const u16*)p + idx);
  }
  return r;
}
__device__ __forceinline__ float loadf(const void* p, size_t idx, int isf32) {
  return isf32 ? ((const float*)p)[idx] : bf2f(((const u16*)p)[idx]);
}

// async global->LDS 16B/lane; LDS dest = wave-uniform base + lane*16.
__device__ __forceinline__ void cp16(const u16* g, u16* l) {
  __builtin_amdgcn_global_load_lds(
      (const __attribute__((address_space(1))) u32*)g,
      (__attribute__((address_space(3))) u32*)l, 16, 0, 0);
}

// ---------------------------------------------------------------------------
// Dtype detector (R3-proven): flags[0]=1 if inputs fp32, flags[1]=0.
// ---------------------------------------------------------------------------
__global__ void detect_dtype(const u16* __restrict__ x, int* __restrict__ flags) {
  int cnt = 0;
  for (int i = threadIdx.x; i < 4096; i += 64) {
    int e = (x[i] >> 7) & 0xFF;
    if (e >= 0xF0) cnt++;
  }
  unsigned long long any = __ballot(cnt > 0);
  if (threadIdx.x == 0) {
    flags[0] = (any != 0ull) ? 1 : 0;
    flags[1] = 0;
  }
}

// ---------------------------------------------------------------------------
// convert_x -> TILED bf16 layout: xb_t[mB][kB][kq][r][8], tile = 128 rows x
// 32 k (8KB). Writes contiguous (tid*8).
// ---------------------------------------------------------------------------
__global__ __launch_bounds__(256) void convert_x(const void* __restrict__ x,
                                                 const int* __restrict__ fp,
                                                 u16* __restrict__ xb) {
  int tid = blockIdx.x * 256 + threadIdx.x;  // 0..524287
  int r = tid & 127, kq = (tid >> 7) & 3, kB = (tid >> 9) & 31, mB = tid >> 14;
  size_t src = (size_t)(mB * 128 + r) * 1024 + kB * 32 + kq * 8;
  *(s16x8*)(xb + (size_t)tid * 8) = load8(x, src, *fp);
}

// ---------------------------------------------------------------------------
// Fused weight transposes into TILED layouts (R18-proven dual format):
//   WqkvT_t[nB(24)][kB(32)][kq(4)][r(128)][8]   (tile rows = 128, NT=128)
//   WprojT_t[nB(16)][kB(32)][kq(4)][r(64)][8]   (tile rows = 64,  NT=64)
// u32-packed conflict-free LDS transpose core. grid (48+16, 16).
// ---------------------------------------------------------------------------
__global__ __launch_bounds__(256) void transposeW2(
    const void* __restrict__ Wqkv, const void* __restrict__ Wproj,
    const int* __restrict__ fp, u16* __restrict__ WqkvT,
    u16* __restrict__ WprojT) {
  __shared__ u32 tile32[32 * 66];
  const int f = *fp;
  const int tid = threadIdx.x;
  const int bx = blockIdx.x;
  const void* W;
  u16* WT;
  int N, nb, qkvSide;
  if (bx < 48) { W = Wqkv; WT = WqkvT; N = 3072; nb = bx * 64; qkvSide = 1; }
  else         { W = Wproj; WT = WprojT; N = 1024; nb = (bx - 48) * 64; qkvSide = 0; }
  const int kb = blockIdx.y * 64;  // K = 1024
  {
    int a = tid >> 3, c8 = tid & 7;
    s16x8 r0 = load8(W, (size_t)(kb + 2 * a) * N + nb + c8 * 8, f);
    s16x8 r1 = load8(W, (size_t)(kb + 2 * a + 1) * N + nb + c8 * 8, f);
#pragma unroll
    for (int j = 0; j < 8; j++)
      tile32[a * 66 + c8 * 8 + j] = (u32)(u16)r0[j] | ((u32)(u16)r1[j] << 16);
  }
  __syncthreads();
#pragma unroll
  for (int i = 0; i < 2; i++) {
    int idx = tid + i * 256;
    int n = idx & 63, c8 = idx >> 6;  // n fast -> contiguous tiled stores
    s16x8 v;
#pragma unroll
    for (int w = 0; w < 4; w++) {
      u32 pk = tile32[(c8 * 4 + w) * 66 + n];
      v[2 * w] = (short)(u16)(pk & 0xFFFF);
      v[2 * w + 1] = (short)(u16)(pk >> 16);
    }
    int R = nb + n, k = kb + c8 * 8;
    int kB = k >> 5, kq = (k >> 3) & 3;
    size_t off;
    if (qkvSide) {
      int nB = R >> 7, r = R & 127;
      off = ((size_t)(nB * 32 + kB) * 4 + kq) * 1024 + r * 8;
    } else {
      int nB = R >> 6, r = R & 63;
      off = (size_t)(nB * 32 + kB) * 2048 + kq * 512 + r * 8;
    }
    *(s16x8*)(WT + off) = v;
  }
}

// ---------------------------------------------------------------------------
// GEMM: C = A @ Bt^T + bias. MB x NT tile, BK-wide K steps. R16-proven
// skeleton (single LDS buffer, syncthreads->stage->syncthreads->compute,
// no swizzle/vmcnt asm). QKV = exact R18 config (NT=128, BK=64, 6 blk/CU).
// R20: proj gets BK=128 -> 8 K-step drains (was 16); LDS 32KB still >= the
// grid-capped 4 blocks/CU, so no occupancy cost (R16 lever extended).
// ATILED=1: A pre-tiled [mB][kB][kq][r(128)][8] (64-row half per block).
// ATILED=2: A tiled-packed in qkv V-columns (R17-proven), 1KB cp16/wave.
// V-FUSION (R18-proven): QKV blocks with n0>=2048 transpose their 64x128
//   tile via LDS and write vT directly.
// ---------------------------------------------------------------------------
template <int MB, int NT, int KK, int ATILED, int BK>
__global__ __launch_bounds__(256, 6) void gemm_bt(
    const u16* __restrict__ A, int lda, const u16* __restrict__ Bt,
    const void* __restrict__ bias, const int* __restrict__ fI32,
    void* __restrict__ C, int ropeMode, int outF,
    const void* __restrict__ cost, const void* __restrict__ sint, int N,
    u16* __restrict__ vout) {
  constexpr int MT = MB / 32;    // m fragments per wave
  constexpr int NTW = NT / 32;   // n fragments per wave
  constexpr int KSUB = BK / 32;  // 32-k chunks per step
  constexpr int KT = KK / BK;    // K steps
  constexpr int APW = MB / 64;   // A cp16 per wave per 32-k chunk
  constexpr int BPW = NT / 64;   // B cp16 per wave per 32-k chunk
  __shared__ __attribute__((aligned(16))) u16 sh[KSUB * (MB + NT) * 32];
  u16* As = sh;
  u16* Bs = sh + KSUB * MB * 32;
  const int inf32 = *fI32;
  const int tid = threadIdx.x;
  const int wave = tid >> 6, lane = tid & 63, quad = lane >> 4, l16 = lane & 15;
  const int bx = blockIdx.x, by = blockIdx.y;
  const int m0 = by * MB, n0 = bx * NT;
  const int wm = (wave & 1) * (MB / 2), wn = (wave >> 1) * (NT / 2);
  f32x4 acc[MT][NTW];
#pragma unroll
  for (int i = 0; i < MT; i++)
#pragma unroll
    for (int j = 0; j < NTW; j++) acc[i][j] = (f32x4){0.f, 0.f, 0.f, 0.f};

  // staging source pointers (per-lane); LDS dests are wave-uniform.
  const u16* aT = nullptr;
  const u16* aP = nullptr;
  int mBv = 0, halfA = 0;
  if constexpr (ATILED == 1) {
    mBv = (MB == 128) ? by : (by >> 1);
    halfA = (MB == 128) ? 0 : (by & 1);
    aT = A + (size_t)mBv * KK * 128 + lane * 8;
  } else if constexpr (ATILED == 2) {
    mBv = by >> 1;
    halfA = by & 1;
    aT = A + lane * 8;  // A = base of packed V-column region (qkv+2048)
  } else {
    const int lr = lane >> 2, lk = (lane & 3) * 8;
    aP = A + (size_t)(m0 + wave * (MB / 4) + lr) * lda + lk;
  }
  const u16* bT = Bt + (size_t)bx * KK * NT + lane * 8;

  for (int s = 0; s < KT; ++s) {
    __syncthreads();
#pragma unroll
    for (int ks = 0; ks < KSUB; ks++) {
      const int kb32 = s * KSUB + ks;  // global 32-k block index
      if constexpr (ATILED == 1) {
#pragma unroll
        for (int j = 0; j < APW; j++) {
          const int c = wave * APW + j;
          size_t off;
          if constexpr (MB == 128) off = (size_t)kb32 * 4096 + c * 512;
          else                     off = (size_t)kb32 * 4096 + c * 1024 + halfA * 512;
          cp16(aT + off, As + ks * (MB * 32) + c * 512);
        }
      } else if constexpr (ATILED == 2) {
        // chunk (mBv, kb32, kq=wave) lives at virtual row vr, 1KB contiguous
        const int vr = mBv * 128 + kb32 * 4 + wave;
        cp16(aT + (size_t)vr * 3072 + halfA * 512,
             As + ks * (MB * 32) + wave * 512);
      } else {
#pragma unroll
        for (int j = 0; j < APW; j++)
          cp16(aP + kb32 * 32 + (size_t)(16 * j) * lda,
               As + ks * (MB * 32) + wave * (APW * 512) + j * 512);
      }
#pragma unroll
      for (int j = 0; j < BPW; j++) {
        const int c = wave * BPW + j;
        cp16(bT + (size_t)kb32 * (NT * 32) + c * 512,
             Bs + ks * (NT * 32) + c * 512);
      }
    }
    __syncthreads();
#pragma unroll
    for (int ks = 0; ks < KSUB; ks++) {
      s16x8 af[MT], bfr[NTW];
#pragma unroll
      for (int mt = 0; mt < MT; mt++) {
        if constexpr (ATILED != 0)
          af[mt] = *(const s16x8*)(As + ks * (MB * 32) + quad * (MB * 8) +
                                   (wm + mt * 16 + l16) * 8);
        else
          af[mt] = *(const s16x8*)(As + ks * (MB * 32) +
                                   (wm + mt * 16 + l16) * 32 + quad * 8);
      }
#pragma unroll
      for (int nt = 0; nt < NTW; nt++)
        bfr[nt] = *(const s16x8*)(Bs + ks * (NT * 32) + quad * (NT * 8) +
                                  (wn + nt * 16 + l16) * 8);
#pragma unroll
      for (int mt = 0; mt < MT; mt++)
#pragma unroll
        for (int nt = 0; nt < NTW; nt++)
          acc[mt][nt] = __builtin_amdgcn_mfma_f32_16x16x32_bf16(
              af[mt], bfr[nt], acc[mt][nt], 0, 0, 0);
    }
  }

  if (ropeMode && n0 >= 2048) {
    // R18 V-fusion: transpose 64x128 tile via LDS (stride 72 = 16B-aligned,
    // 2-way-max banks), write vT directly. sh is dead after the barrier.
    __syncthreads();
    u16* T = sh;  // needs 128*72 = 9216 u16 <= 12288
#pragma unroll
    for (int nt = 0; nt < NTW; nt++) {
      const int colL = wn + nt * 16 + l16;
      float bv = loadf(bias, n0 + colL, inf32);
#pragma unroll
      for (int mt = 0; mt < MT; mt++)
#pragma unroll
        for (int r = 0; r < 4; r++)
          T[colL * 72 + wm + mt * 16 + quad * 4 + r] =
              f2bf(acc[mt][nt][r] + bv);
    }
    __syncthreads();
    const int b = m0 >> 11, t0 = m0 & 2047, h0 = (n0 - 2048) >> 6;
    const int hd = tid >> 1, seg = tid & 1;
    const int h = h0 + (hd >> 6), d = hd & 63;
    u16* dst = vout + ((size_t)((b * 16 + h) * 64 + d)) * 2048 + t0 + seg * 32;
    const u16* src = T + hd * 72 + seg * 32;
    *(s16x8*)(dst) = *(const s16x8*)(src);
    *(s16x8*)(dst + 8) = *(const s16x8*)(src + 8);
    *(s16x8*)(dst + 16) = *(const s16x8*)(src + 16);
    *(s16x8*)(dst + 24) = *(const s16x8*)(src + 24);
    return;
  }

#pragma unroll
  for (int nt = 0; nt < NTW; nt++) {
    int col = n0 + wn + nt * 16 + l16;
    float bv = loadf(bias, col, inf32);
    if (ropeMode && col < 2048) {
      int j = (col & 63) >> 1, odd = col & 1;
#pragma unroll
      for (int mt = 0; mt < MT; mt++)
#pragma unroll
        for (int r = 0; r < 4; r++) {
          int row = m0 + wm + mt * 16 + quad * 4 + r, t = row & 2047;
          float cv = loadf(cost, (size_t)t * 32 + j, inf32);
          float sv = loadf(sint, (size_t)t * 32 + j, inf32);
          float val = acc[mt][nt][r] + bv;
          float pr = __shfl_xor(val, 1);
          float res = odd ? (pr * sv + val * cv) : (val * cv - pr * sv);
          ((u16*)C)[(size_t)row * N + col] = f2bf(res);
        }
    } else if (outF && inf32) {  // final output, fp32
#pragma unroll
      for (int mt = 0; mt < MT; mt++)
#pragma unroll
        for (int r = 0; r < 4; r++) {
          int row = m0 + wm + mt * 16 + quad * 4 + r;
          ((float*)C)[(size_t)row * N + col] = acc[mt][nt][r] + bv;
        }
    } else {
#pragma unroll
      for (int mt = 0; mt < MT; mt++)
#pragma unroll
        for (int r = 0; r < 4; r++) {
          int row = m0 + wm + mt * 16 + quad * 4 + r;
          ((u16*)C)[(size_t)row * N + col] = f2bf(acc[mt][nt][r] + bv);
        }
    }
  }
}

// ---------------------------------------------------------------------------
// Causal flash attention v5 (R14-proven core, conflicts 0; R18-proven
// LDS-packed y write-out: 8 x 2KB contiguous runs feeding proj's ATILED=2).
// ---------------------------------------------------------------------------
__device__ __forceinline__ int kvIdx(int chunk, int row) {  // 64-row tile
  return chunk * 512 + (((row & 56) | ((row ^ chunk) & 7)) << 3);
}
__device__ __forceinline__ int pIdx(int chunk, int row) {   // 16-row tile
  return chunk * 128 + (((row & 8) | ((row ^ chunk) & 7)) << 3);
}

__global__ __launch_bounds__(512) void attn_kernel(u16* qkv,
                                                   const u16* __restrict__ vT) {
  __shared__ __attribute__((aligned(16))) u16 Ks[8 * 512];
  __shared__ __attribute__((aligned(16))) u16 Vt[8 * 512];
  __shared__ __attribute__((aligned(16))) u16 Pl[8][8 * 128];
  const int tid = threadIdx.x;
  const int wave = tid >> 6, lane = tid & 63, quad = lane >> 4, l16 = lane & 15;
  const int cu = blockIdx.x & 255, round = blockIdx.x >> 8;
  const int p = cu >> 5, bh = cu & 31;
  const int qt = round ? p : 15 - p;  // heavy first
  const int h = bh & 15;
  const size_t rb = (size_t)(bh >> 4) * 2048;
  const int qb = qt * 128;
  const float SCALE = 0.18033688011112042f;  // 0.125 * log2(e)

  // Q fragment for this wave's 16 rows (direct from global, once)
  s16x8 qa0, qa1;
  {
    const u16* qp = qkv + (rb + qb + wave * 16 + l16) * 3072 + h * 64;
    qa0 = *(const s16x8*)(qp + quad * 8);
    qa1 = *(const s16x8*)(qp + 32 + quad * 8);
  }

  f32x4 o[4];
  float l_r[4] = {0.f, 0.f, 0.f, 0.f};
#pragma unroll
  for (int i = 0; i < 4; i++) o[i] = (f32x4){0.f, 0.f, 0.f, 0.f};

  const int nchunks = 2 * qt + 2;
  const int srow = tid >> 3, sc8 = tid & 7;  // 64 rows x 8 d-chunks staging
  const int stIdx = kvIdx(sc8, srow);        // swizzled staging granule
  s16x8 kr, vr;
  {
    kr = *(const s16x8*)(qkv + (rb + srow) * 3072 + 1024 + h * 64 + sc8 * 8);
    vr = *(const s16x8*)(vT + ((size_t)bh * 64 + srow) * 2048 + sc8 * 8);
  }

  for (int c = 0; c < nchunks; c++) {
    const int sb = c * 64;
    __syncthreads();  // previous compute done reading Ks/Vt
    *(s16x8*)(Ks + stIdx) = kr;
    *(s16x8*)(Vt + stIdx) = vr;
    __syncthreads();
    if (c + 1 < nchunks) {  // next chunk's global loads overlap compute
      const int nb = sb + 64;
      kr = *(const s16x8*)(qkv + (rb + nb + srow) * 3072 + 1024 + h * 64 +
                           sc8 * 8);
      vr = *(const s16x8*)(vT + ((size_t)bh * 64 + srow) * 2048 + nb + sc8 * 8);
    }

    // waves whose query range is entirely below this key chunk contribute 0
    if (sb > qb + wave * 16 + 15) continue;

    f32x4 S[4];
#pragma unroll
    for (int kf = 0; kf < 4; kf++) {
      s16x8 k0 = *(const s16x8*)(Ks + kvIdx(quad, kf * 16 + l16));
      s16x8 k1 = *(const s16x8*)(Ks + kvIdx(quad + 4, kf * 16 + l16));
      f32x4 a = (f32x4){0.f, 0.f, 0.f, 0.f};
      a = __builtin_amdgcn_mfma_f32_16x16x32_bf16(qa0, k0, a, 0, 0, 0);
      a = __builtin_amdgcn_mfma_f32_16x16x32_bf16(qa1, k1, a, 0, 0, 0);
      S[kf] = a;
    }

    // exp, mask-select, per-lane l accumulation, P write, single wait
    u16* P = Pl[wave];
    const int mq = qb + wave * 16;
    const bool needMask = (sb + 63) > mq;  // wave-uniform
#pragma unroll
    for (int r = 0; r < 4; r++) {
      const int qi = mq + quad * 4 + r;
#pragma unroll
      for (int kf = 0; kf < 4; kf++) {
        float pv = __builtin_amdgcn_exp2f(S[kf][r] * SCALE);
        if (needMask) pv = ((sb + kf * 16 + l16) <= qi) ? pv : 0.f;
        l_r[r] += pv;
        P[pIdx(kf * 2 + (l16 >> 3), quad * 4 + r) + (l16 & 7)] = f2bf_fast(pv);
      }
    }
    asm volatile("s_waitcnt lgkmcnt(0)" ::: "memory");
    s16x8 pa0 = *(const s16x8*)(P + pIdx(quad, l16));
    s16x8 pa1 = *(const s16x8*)(P + pIdx(quad + 4, l16));

#pragma unroll
    for (int dt = 0; dt < 4; dt++) {
      s16x8 vb0 = *(const s16x8*)(Vt + kvIdx(quad, dt * 16 + l16));
      s16x8 vb1 = *(const s16x8*)(Vt + kvIdx(quad + 4, dt * 16 + l16));
      o[dt] = __builtin_amdgcn_mfma_f32_16x16x32_bf16(pa0, vb0, o[dt], 0, 0, 0);
      o[dt] = __builtin_amdgcn_mfma_f32_16x16x32_bf16(pa1, vb1, o[dt], 0, 0, 0);
    }
  }

  // deferred cross-lane l reduction
  float inv[4];
#pragma unroll
  for (int r = 0; r < 4; r++) {
    float rs = l_r[r];
#pragma unroll
    for (int off = 8; off; off >>= 1) rs += __shfl_xor(rs, off);
    inv[r] = 1.0f / fmaxf(rs, 1e-30f);
  }

  // pack y into dead Ks/Vt LDS ([g][rowL][8]), then 8x2KB coalesced runs
  __syncthreads();  // all waves done reading Ks/Vt
#pragma unroll
  for (int dt = 0; dt < 4; dt++) {
    u16* base = (dt < 2) ? Ks : Vt;
    const int gl = (dt & 1) * 2 + (l16 >> 3);  // group within half
#pragma unroll
    for (int r = 0; r < 4; r++) {
      const int rowL = wave * 16 + quad * 4 + r;
      base[gl * 1024 + rowL * 8 + (l16 & 7)] = f2bf(o[dt][r] * inv[r]);
    }
  }
  __syncthreads();
  {
    const int g = tid >> 6, part = tid & 63;
    const u16* src = (g < 4 ? Ks + g * 1024 : Vt + (g - 4) * 1024) + part * 16;
    const int vrow = ((int)(rb >> 7) + qt) * 128 + h * 8 + g;
    u16* dst = qkv + (size_t)vrow * 3072 + 2048 + part * 16;
    *(s16x8*)(dst) = *(const s16x8*)(src);
    *(s16x8*)(dst + 8) = *(const s16x8*)(src + 8);
  }
}

extern "C" void kernel_launch(void* const* d_in, const int* in_sizes, int n_in,
                              void* d_out, int out_size, void* d_ws,
                              size_t ws_size, hipStream_t stream) {
  const void* x = d_in[0];
  const void* Wqkv = d_in[1];
  const void* bqkv = d_in[2];
  const void* Wproj = d_in[3];
  const void* bproj = d_in[4];
  const void* cost = d_in[5];
  const void* sint = d_in[6];

  int* flags = (int*)d_ws;
  u16* WqkvT = (u16*)d_ws + 128;               // tiled [24][32][4][128][8]
  u16* WprojT = WqkvT + (size_t)3072 * 1024;   // tiled [16][32][4][64][8]
  u16* qkv = WprojT + (size_t)1024 * 1024;     // [4096][3072] bf16 row-major
  u16* yb = qkv + 2048;                        // y tiled-packed in the dead
                                               //   V-columns (R17 layout)
  u16* xb = (u16*)d_out;                       // tiled [32][32][4][128][8]
  u16* vT = (u16*)d_out + (size_t)4096 * 1024; // V^T (upper half; dead before
                                               //   final fp32 write)

  detect_dtype<<<1, 64, 0, stream>>>((const u16*)x, flags);
  convert_x<<<2048, 256, 0, stream>>>(x, flags, xb);
  transposeW2<<<dim3(64, 16), 256, 0, stream>>>(Wqkv, Wproj, flags, WqkvT,
                                                WprojT);
  gemm_bt<64, 128, 1024, 1, 64><<<dim3(24, 64), 256, 0, stream>>>(
      xb, 1024, WqkvT, bqkv, flags, qkv, 1, 0, cost, sint, 3072, vT);
  attn_kernel<<<512, 512, 0, stream>>>(qkv, vT);
  gemm_bt<64, 64, 1024, 2, 128><<<dim3(16, 64), 256, 0, stream>>>(
      yb, 3072, WprojT, bproj, flags, d_out, 0, 1, nullptr, nullptr, 1024,
      nullptr);
}

// Round 14
// 188.218 us; speedup vs baseline: 1.0730x; 1.0730x over previous
//
#include <hip/hip_runtime.h>
#include <stdint.h>

typedef short s16x8 __attribute__((ext_vector_type(8)));
typedef float f32x4 __attribute__((ext_vector_type(4)));
typedef unsigned short u16;
typedef unsigned int u32;

__device__ __forceinline__ float bf2f(u16 u) {
  union { u32 i; float f; } v; v.i = ((u32)u) << 16; return v.f;
}
__device__ __forceinline__ u16 f2bf(float f) {  // round-to-nearest-even
  union { float f; u32 i; } v; v.f = f;
  u32 i = v.i;
  return (u16)((i + 0x7fffu + ((i >> 16) & 1u)) >> 16);
}
__device__ __forceinline__ u16 f2bf_fast(float f) {  // round-half-up
  union { float f; u32 i; } v; v.f = f;
  return (u16)((v.i + 0x8000u) >> 16);
}

__device__ __forceinline__ s16x8 load8(const void* p, size_t idx, int isf32) {
  s16x8 r;
  if (isf32) {
    const float* f = (const float*)p + idx;
    f32x4 a = *(const f32x4*)f;
    f32x4 b = *(const f32x4*)(f + 4);
#pragma unroll
    for (int j = 0; j < 4; j++) {
      r[j] = (short)f2bf(a[j]);
      r[4 + j] = (short)f2bf(b[j]);
    }
  } else {
    r = *(const s16x8*)((const u16*)p + idx);
  }
  return r;
}
__device__ __forceinline__ float loadf(const void* p, size_t idx, int isf32) {
  return isf32 ? ((const float*)p)[idx] : bf2f(((const u16*)p)[idx]);
}

// async global->LDS 16B/lane; LDS dest = wave-uniform base + lane*16.
__device__ __forceinline__ void cp16(const u16* g, u16* l) {
  __builtin_amdgcn_global_load_lds(
      (const __attribute__((address_space(1))) u32*)g,
      (__attribute__((address_space(3))) u32*)l, 16, 0, 0);
}

// ---------------------------------------------------------------------------
// R21 fused prep kernel: detect_dtype + convert_x + transposeW2 in ONE
// launch (was 3). grid 3072x256:
//   every block: dtype flag from x[0:4096) u16 (8KB, L2-broadcast, ~free);
//                block 0 publishes flags[] for the downstream GEMMs.
//   bx <  2048 : convert_x body (R10-proven tiled xb writer)
//   bx >= 2048 : transposeW2 body (R4/R18-proven dual-format W transpose),
//                tbx = (bx-2048)&63, tby = (bx-2048)>>6  (orig grid (64,16))
// ---------------------------------------------------------------------------
__global__ __launch_bounds__(256) void prep(
    const void* __restrict__ x, const void* __restrict__ Wqkv,
    const void* __restrict__ Wproj, u16* __restrict__ xb,
    u16* __restrict__ WqkvT, u16* __restrict__ WprojT,
    int* __restrict__ flags) {
  __shared__ u32 tile32[32 * 66];
  __shared__ int fsh[4];
  const int tid = threadIdx.x;
  const int bx = blockIdx.x;
  {
    const u16* xu = (const u16*)x;
    int cnt = 0;
    for (int i = tid; i < 4096; i += 256) {
      int e = (xu[i] >> 7) & 0xFF;
      if (e >= 0xF0) cnt++;
    }
    unsigned long long any = __ballot(cnt > 0);
    if ((tid & 63) == 0) fsh[tid >> 6] = (any != 0ull) ? 1 : 0;
  }
  __syncthreads();
  const int f = fsh[0] | fsh[1] | fsh[2] | fsh[3];
  if (bx == 0 && tid == 0) { flags[0] = f; flags[1] = 0; }

  if (bx < 2048) {
    // convert_x: x -> tiled xb_t[mB][kB][kq][r][8]
    int t = bx * 256 + tid;  // 0..524287
    int r = t & 127, kq = (t >> 7) & 3, kB = (t >> 9) & 31, mB = t >> 14;
    size_t src = (size_t)(mB * 128 + r) * 1024 + kB * 32 + kq * 8;
    *(s16x8*)(xb + (size_t)t * 8) = load8(x, src, f);
    return;
  }

  // transposeW2 body
  const int bxp = bx - 2048;
  const int tbx = bxp & 63, tby = bxp >> 6;
  const void* W;
  u16* WT;
  int N, nb, qkvSide;
  if (tbx < 48) { W = Wqkv; WT = WqkvT; N = 3072; nb = tbx * 64; qkvSide = 1; }
  else          { W = Wproj; WT = WprojT; N = 1024; nb = (tbx - 48) * 64; qkvSide = 0; }
  const int kb = tby * 64;  // K = 1024
  {
    int a = tid >> 3, c8 = tid & 7;
    s16x8 r0 = load8(W, (size_t)(kb + 2 * a) * N + nb + c8 * 8, f);
    s16x8 r1 = load8(W, (size_t)(kb + 2 * a + 1) * N + nb + c8 * 8, f);
#pragma unroll
    for (int j = 0; j < 8; j++)
      tile32[a * 66 + c8 * 8 + j] = (u32)(u16)r0[j] | ((u32)(u16)r1[j] << 16);
  }
  __syncthreads();
#pragma unroll
  for (int i = 0; i < 2; i++) {
    int idx = tid + i * 256;
    int n = idx & 63, c8 = idx >> 6;  // n fast -> contiguous tiled stores
    s16x8 v;
#pragma unroll
    for (int w = 0; w < 4; w++) {
      u32 pk = tile32[(c8 * 4 + w) * 66 + n];
      v[2 * w] = (short)(u16)(pk & 0xFFFF);
      v[2 * w + 1] = (short)(u16)(pk >> 16);
    }
    int R = nb + n, k = kb + c8 * 8;
    int kB = k >> 5, kq = (k >> 3) & 3;
    size_t off;
    if (qkvSide) {
      int nB = R >> 7, r = R & 127;
      off = ((size_t)(nB * 32 + kB) * 4 + kq) * 1024 + r * 8;
    } else {
      int nB = R >> 6, r = R & 63;
      off = (size_t)(nB * 32 + kB) * 2048 + kq * 512 + r * 8;
    }
    *(s16x8*)(WT + off) = v;
  }
}

// ---------------------------------------------------------------------------
// GEMM: C = A @ Bt^T + bias. MB x NT tile, BK-wide K steps. R16-proven
// skeleton (single LDS buffer, syncthreads->stage->syncthreads->compute,
// no swizzle/vmcnt asm). QKV = R18 config (NT=128, BK=64, 6 blk/CU).
// Proj = R20 config (NT=64, BK=128, ATILED=2).
// ATILED=1: A pre-tiled [mB][kB][kq][r(128)][8] (64-row half per block).
// ATILED=2: A tiled-packed in qkv V-columns (R17-proven), 1KB cp16/wave.
// V-FUSION (R18-proven): QKV blocks with n0>=2048 transpose their 64x128
//   tile via LDS and write vT directly.
// ---------------------------------------------------------------------------
template <int MB, int NT, int KK, int ATILED, int BK>
__global__ __launch_bounds__(256, 6) void gemm_bt(
    const u16* __restrict__ A, int lda, const u16* __restrict__ Bt,
    const void* __restrict__ bias, const int* __restrict__ fI32,
    void* __restrict__ C, int ropeMode, int outF,
    const void* __restrict__ cost, const void* __restrict__ sint, int N,
    u16* __restrict__ vout) {
  constexpr int MT = MB / 32;    // m fragments per wave
  constexpr int NTW = NT / 32;   // n fragments per wave
  constexpr int KSUB = BK / 32;  // 32-k chunks per step
  constexpr int KT = KK / BK;    // K steps
  constexpr int APW = MB / 64;   // A cp16 per wave per 32-k chunk
  constexpr int BPW = NT / 64;   // B cp16 per wave per 32-k chunk
  __shared__ __attribute__((aligned(16))) u16 sh[KSUB * (MB + NT) * 32];
  u16* As = sh;
  u16* Bs = sh + KSUB * MB * 32;
  const int inf32 = *fI32;
  const int tid = threadIdx.x;
  const int wave = tid >> 6, lane = tid & 63, quad = lane >> 4, l16 = lane & 15;
  const int bx = blockIdx.x, by = blockIdx.y;
  const int m0 = by * MB, n0 = bx * NT;
  const int wm = (wave & 1) * (MB / 2), wn = (wave >> 1) * (NT / 2);
  f32x4 acc[MT][NTW];
#pragma unroll
  for (int i = 0; i < MT; i++)
#pragma unroll
    for (int j = 0; j < NTW; j++) acc[i][j] = (f32x4){0.f, 0.f, 0.f, 0.f};

  // staging source pointers (per-lane); LDS dests are wave-uniform.
  const u16* aT = nullptr;
  const u16* aP = nullptr;
  int mBv = 0, halfA = 0;
  if constexpr (ATILED == 1) {
    mBv = (MB == 128) ? by : (by >> 1);
    halfA = (MB == 128) ? 0 : (by & 1);
    aT = A + (size_t)mBv * KK * 128 + lane * 8;
  } else if constexpr (ATILED == 2) {
    mBv = by >> 1;
    halfA = by & 1;
    aT = A + lane * 8;  // A = base of packed V-column region (qkv+2048)
  } else {
    const int lr = lane >> 2, lk = (lane & 3) * 8;
    aP = A + (size_t)(m0 + wave * (MB / 4) + lr) * lda + lk;
  }
  const u16* bT = Bt + (size_t)bx * KK * NT + lane * 8;

  for (int s = 0; s < KT; ++s) {
    __syncthreads();
#pragma unroll
    for (int ks = 0; ks < KSUB; ks++) {
      const int kb32 = s * KSUB + ks;  // global 32-k block index
      if constexpr (ATILED == 1) {
#pragma unroll
        for (int j = 0; j < APW; j++) {
          const int c = wave * APW + j;
          size_t off;
          if constexpr (MB == 128) off = (size_t)kb32 * 4096 + c * 512;
          else                     off = (size_t)kb32 * 4096 + c * 1024 + halfA * 512;
          cp16(aT + off, As + ks * (MB * 32) + c * 512);
        }
      } else if constexpr (ATILED == 2) {
        // chunk (mBv, kb32, kq=wave) lives at virtual row vr, 1KB contiguous
        const int vr = mBv * 128 + kb32 * 4 + wave;
        cp16(aT + (size_t)vr * 3072 + halfA * 512,
             As + ks * (MB * 32) + wave * 512);
      } else {
#pragma unroll
        for (int j = 0; j < APW; j++)
          cp16(aP + kb32 * 32 + (size_t)(16 * j) * lda,
               As + ks * (MB * 32) + wave * (APW * 512) + j * 512);
      }
#pragma unroll
      for (int j = 0; j < BPW; j++) {
        const int c = wave * BPW + j;
        cp16(bT + (size_t)kb32 * (NT * 32) + c * 512,
             Bs + ks * (NT * 32) + c * 512);
      }
    }
    __syncthreads();
#pragma unroll
    for (int ks = 0; ks < KSUB; ks++) {
      s16x8 af[MT], bfr[NTW];
#pragma unroll
      for (int mt = 0; mt < MT; mt++) {
        if constexpr (ATILED != 0)
          af[mt] = *(const s16x8*)(As + ks * (MB * 32) + quad * (MB * 8) +
                                   (wm + mt * 16 + l16) * 8);
        else
          af[mt] = *(const s16x8*)(As + ks * (MB * 32) +
                                   (wm + mt * 16 + l16) * 32 + quad * 8);
      }
#pragma unroll
      for (int nt = 0; nt < NTW; nt++)
        bfr[nt] = *(const s16x8*)(Bs + ks * (NT * 32) + quad * (NT * 8) +
                                  (wn + nt * 16 + l16) * 8);
#pragma unroll
      for (int mt = 0; mt < MT; mt++)
#pragma unroll
        for (int nt = 0; nt < NTW; nt++)
          acc[mt][nt] = __builtin_amdgcn_mfma_f32_16x16x32_bf16(
              af[mt], bfr[nt], acc[mt][nt], 0, 0, 0);
    }
  }

  if (ropeMode && n0 >= 2048) {
    // R18 V-fusion: transpose 64x128 tile via LDS (stride 72 = 16B-aligned,
    // 2-way-max banks), write vT directly. sh is dead after the barrier.
    __syncthreads();
    u16* T = sh;  // needs 128*72 = 9216 u16 <= 12288
#pragma unroll
    for (int nt = 0; nt < NTW; nt++) {
      const int colL = wn + nt * 16 + l16;
      float bv = loadf(bias, n0 + colL, inf32);
#pragma unroll
      for (int mt = 0; mt < MT; mt++)
#pragma unroll
        for (int r = 0; r < 4; r++)
          T[colL * 72 + wm + mt * 16 + quad * 4 + r] =
              f2bf(acc[mt][nt][r] + bv);
    }
    __syncthreads();
    const int b = m0 >> 11, t0 = m0 & 2047, h0 = (n0 - 2048) >> 6;
    const int hd = tid >> 1, seg = tid & 1;
    const int h = h0 + (hd >> 6), d = hd & 63;
    u16* dst = vout + ((size_t)((b * 16 + h) * 64 + d)) * 2048 + t0 + seg * 32;
    const u16* src = T + hd * 72 + seg * 32;
    *(s16x8*)(dst) = *(const s16x8*)(src);
    *(s16x8*)(dst + 8) = *(const s16x8*)(src + 8);
    *(s16x8*)(dst + 16) = *(const s16x8*)(src + 16);
    *(s16x8*)(dst + 24) = *(const s16x8*)(src + 24);
    return;
  }

#pragma unroll
  for (int nt = 0; nt < NTW; nt++) {
    int col = n0 + wn + nt * 16 + l16;
    float bv = loadf(bias, col, inf32);
    if (ropeMode && col < 2048) {
      int j = (col & 63) >> 1, odd = col & 1;
#pragma unroll
      for (int mt = 0; mt < MT; mt++)
#pragma unroll
        for (int r = 0; r < 4; r++) {
          int row = m0 + wm + mt * 16 + quad * 4 + r, t = row & 2047;
          float cv = loadf(cost, (size_t)t * 32 + j, inf32);
          float sv = loadf(sint, (size_t)t * 32 + j, inf32);
          float val = acc[mt][nt][r] + bv;
          float pr = __shfl_xor(val, 1);
          float res = odd ? (pr * sv + val * cv) : (val * cv - pr * sv);
          ((u16*)C)[(size_t)row * N + col] = f2bf(res);
        }
    } else if (outF && inf32) {  // final output, fp32
#pragma unroll
      for (int mt = 0; mt < MT; mt++)
#pragma unroll
        for (int r = 0; r < 4; r++) {
          int row = m0 + wm + mt * 16 + quad * 4 + r;
          ((float*)C)[(size_t)row * N + col] = acc[mt][nt][r] + bv;
        }
    } else {
#pragma unroll
      for (int mt = 0; mt < MT; mt++)
#pragma unroll
        for (int r = 0; r < 4; r++) {
          int row = m0 + wm + mt * 16 + quad * 4 + r;
          ((u16*)C)[(size_t)row * N + col] = f2bf(acc[mt][nt][r] + bv);
        }
    }
  }
}

// ---------------------------------------------------------------------------
// Causal flash attention v5 (R14-proven core, conflicts 0; R18-proven
// LDS-packed y write-out: 8 x 2KB contiguous runs feeding proj's ATILED=2).
// ---------------------------------------------------------------------------
__device__ __forceinline__ int kvIdx(int chunk, int row) {  // 64-row tile
  return chunk * 512 + (((row & 56) | ((row ^ chunk) & 7)) << 3);
}
__device__ __forceinline__ int pIdx(int chunk, int row) {   // 16-row tile
  return chunk * 128 + (((row & 8) | ((row ^ chunk) & 7)) << 3);
}

__global__ __launch_bounds__(512) void attn_kernel(u16* qkv,
                                                   const u16* __restrict__ vT) {
  __shared__ __attribute__((aligned(16))) u16 Ks[8 * 512];
  __shared__ __attribute__((aligned(16))) u16 Vt[8 * 512];
  __shared__ __attribute__((aligned(16))) u16 Pl[8][8 * 128];
  const int tid = threadIdx.x;
  const int wave = tid >> 6, lane = tid & 63, quad = lane >> 4, l16 = lane & 15;
  const int cu = blockIdx.x & 255, round = blockIdx.x >> 8;
  const int p = cu >> 5, bh = cu & 31;
  const int qt = round ? p : 15 - p;  // heavy first
  const int h = bh & 15;
  const size_t rb = (size_t)(bh >> 4) * 2048;
  const int qb = qt * 128;
  const float SCALE = 0.18033688011112042f;  // 0.125 * log2(e)

  // Q fragment for this wave's 16 rows (direct from global, once)
  s16x8 qa0, qa1;
  {
    const u16* qp = qkv + (rb + qb + wave * 16 + l16) * 3072 + h * 64;
    qa0 = *(const s16x8*)(qp + quad * 8);
    qa1 = *(const s16x8*)(qp + 32 + quad * 8);
  }

  f32x4 o[4];
  float l_r[4] = {0.f, 0.f, 0.f, 0.f};
#pragma unroll
  for (int i = 0; i < 4; i++) o[i] = (f32x4){0.f, 0.f, 0.f, 0.f};

  const int nchunks = 2 * qt + 2;
  const int srow = tid >> 3, sc8 = tid & 7;  // 64 rows x 8 d-chunks staging
  const int stIdx = kvIdx(sc8, srow);        // swizzled staging granule
  s16x8 kr, vr;
  {
    kr = *(const s16x8*)(qkv + (rb + srow) * 3072 + 1024 + h * 64 + sc8 * 8);
    vr = *(const s16x8*)(vT + ((size_t)bh * 64 + srow) * 2048 + sc8 * 8);
  }

  for (int c = 0; c < nchunks; c++) {
    const int sb = c * 64;
    __syncthreads();  // previous compute done reading Ks/Vt
    *(s16x8*)(Ks + stIdx) = kr;
    *(s16x8*)(Vt + stIdx) = vr;
    __syncthreads();
    if (c + 1 < nchunks) {  // next chunk's global loads overlap compute
      const int nb = sb + 64;
      kr = *(const s16x8*)(qkv + (rb + nb + srow) * 3072 + 1024 + h * 64 +
                           sc8 * 8);
      vr = *(const s16x8*)(vT + ((size_t)bh * 64 + srow) * 2048 + nb + sc8 * 8);
    }

    // waves whose query range is entirely below this key chunk contribute 0
    if (sb > qb + wave * 16 + 15) continue;

    f32x4 S[4];
#pragma unroll
    for (int kf = 0; kf < 4; kf++) {
      s16x8 k0 = *(const s16x8*)(Ks + kvIdx(quad, kf * 16 + l16));
      s16x8 k1 = *(const s16x8*)(Ks + kvIdx(quad + 4, kf * 16 + l16));
      f32x4 a = (f32x4){0.f, 0.f, 0.f, 0.f};
      a = __builtin_amdgcn_mfma_f32_16x16x32_bf16(qa0, k0, a, 0, 0, 0);
      a = __builtin_amdgcn_mfma_f32_16x16x32_bf16(qa1, k1, a, 0, 0, 0);
      S[kf] = a;
    }

    // exp, mask-select, per-lane l accumulation, P write, single wait
    u16* P = Pl[wave];
    const int mq = qb + wave * 16;
    const bool needMask = (sb + 63) > mq;  // wave-uniform
#pragma unroll
    for (int r = 0; r < 4; r++) {
      const int qi = mq + quad * 4 + r;
#pragma unroll
      for (int kf = 0; kf < 4; kf++) {
        float pv = __builtin_amdgcn_exp2f(S[kf][r] * SCALE);
        if (needMask) pv = ((sb + kf * 16 + l16) <= qi) ? pv : 0.f;
        l_r[r] += pv;
        P[pIdx(kf * 2 + (l16 >> 3), quad * 4 + r) + (l16 & 7)] = f2bf_fast(pv);
      }
    }
    asm volatile("s_waitcnt lgkmcnt(0)" ::: "memory");
    s16x8 pa0 = *(const s16x8*)(P + pIdx(quad, l16));
    s16x8 pa1 = *(const s16x8*)(P + pIdx(quad + 4, l16));

#pragma unroll
    for (int dt = 0; dt < 4; dt++) {
      s16x8 vb0 = *(const s16x8*)(Vt + kvIdx(quad, dt * 16 + l16));
      s16x8 vb1 = *(const s16x8*)(Vt + kvIdx(quad + 4, dt * 16 + l16));
      o[dt] = __builtin_amdgcn_mfma_f32_16x16x32_bf16(pa0, vb0, o[dt], 0, 0, 0);
      o[dt] = __builtin_amdgcn_mfma_f32_16x16x32_bf16(pa1, vb1, o[dt], 0, 0, 0);
    }
  }

  // deferred cross-lane l reduction
  float inv[4];
#pragma unroll
  for (int r = 0; r < 4; r++) {
    float rs = l_r[r];
#pragma unroll
    for (int off = 8; off; off >>= 1) rs += __shfl_xor(rs, off);
    inv[r] = 1.0f / fmaxf(rs, 1e-30f);
  }

  // pack y into dead Ks/Vt LDS ([g][rowL][8]), then 8x2KB coalesced runs
  __syncthreads();  // all waves done reading Ks/Vt
#pragma unroll
  for (int dt = 0; dt < 4; dt++) {
    u16* base = (dt < 2) ? Ks : Vt;
    const int gl = (dt & 1) * 2 + (l16 >> 3);  // group within half
#pragma unroll
    for (int r = 0; r < 4; r++) {
      const int rowL = wave * 16 + quad * 4 + r;
      base[gl * 1024 + rowL * 8 + (l16 & 7)] = f2bf(o[dt][r] * inv[r]);
    }
  }
  __syncthreads();
  {
    const int g = tid >> 6, part = tid & 63;
    const u16* src = (g < 4 ? Ks + g * 1024 : Vt + (g - 4) * 1024) + part * 16;
    const int vrow = ((int)(rb >> 7) + qt) * 128 + h * 8 + g;
    u16* dst = qkv + (size_t)vrow * 3072 + 2048 + part * 16;
    *(s16x8*)(dst) = *(const s16x8*)(src);
    *(s16x8*)(dst + 8) = *(const s16x8*)(src + 8);
  }
}

extern "C" void kernel_launch(void* const* d_in, const int* in_sizes, int n_in,
                              void* d_out, int out_size, void* d_ws,
                              size_t ws_size, hipStream_t stream) {
  const void* x = d_in[0];
  const void* Wqkv = d_in[1];
  const void* bqkv = d_in[2];
  const void* Wproj = d_in[3];
  const void* bproj = d_in[4];
  const void* cost = d_in[5];
  const void* sint = d_in[6];

  int* flags = (int*)d_ws;
  u16* WqkvT = (u16*)d_ws + 128;               // tiled [24][32][4][128][8]
  u16* WprojT = WqkvT + (size_t)3072 * 1024;   // tiled [16][32][4][64][8]
  u16* qkv = WprojT + (size_t)1024 * 1024;     // [4096][3072] bf16 row-major
  u16* yb = qkv + 2048;                        // y tiled-packed in the dead
                                               //   V-columns (R17 layout)
  u16* xb = (u16*)d_out;                       // tiled [32][32][4][128][8]
  u16* vT = (u16*)d_out + (size_t)4096 * 1024; // V^T (upper half; dead before
                                               //   final fp32 write)

  prep<<<3072, 256, 0, stream>>>(x, Wqkv, Wproj, xb, WqkvT, WprojT, flags);
  gemm_bt<64, 128, 1024, 1, 64><<<dim3(24, 64), 256, 0, stream>>>(
      xb, 1024, WqkvT, bqkv, flags, qkv, 1, 0, cost, sint, 3072, vT);
  attn_kernel<<<512, 512, 0, stream>>>(qkv, vT);
  gemm_bt<64, 64, 1024, 2, 128><<<dim3(16, 64), 256, 0, stream>>>(
      yb, 3072, WprojT, bproj, flags, d_out, 0, 1, nullptr, nullptr, 1024,
      nullptr);
}